// Round 23
// baseline (373.491 us; speedup 1.0000x reference)
//
#include <hip/hip_runtime.h>
#include <math.h>

#define NB 32
#define NP 24656
#define NO 16
#define NC 81
#define ND 85   // 4 + NC
#define THRESH_F 0.5f
#define NEGPOS_I 3
#define VAR0_F 0.1f
#define VAR1_F 0.2f
#define NEG_HUGE -1e30f

#define BPCNT (NB * NP)
#define CHB32 771              // 32-row chunks per batch row
#define FLAT_TOTAL (NB * CHB32)  // 24672
#define NBLK 1792              // 7 blocks/CU x 256 CU (all co-resident)
#define CB32 11264             // staged bytes per chunk

typedef unsigned long long u64;

// ---------------------------------------------------------------- stage (reg)
__device__ __forceinline__ void stage_load(float4* vreg,
                                           const char* __restrict__ gpred,
                                           int b, int r0, int lane) {
    const size_t off = ((size_t)b * NP + r0) * 340ull;
    const char* g = gpred + off;
    const bool unsafe = (b == NB - 1) && (r0 + 34 > NP);
    if (!unsafe) {
#pragma unroll
        for (int k = 0; k < 11; ++k)
            vreg[k] = *(const float4*)(g + k * 1024 + lane * 16);
    } else {
        const int nf4 = (NP - r0) * ND / 4;
        const float4* gs = (const float4*)g;
#pragma unroll
        for (int k = 0; k < 11; ++k) {
            const int idx = k * 64 + lane;
            vreg[k] = (idx < nf4) ? gs[idx]
                                  : make_float4(0.f, 0.f, 0.f, 0.f);
        }
    }
}

__device__ __forceinline__ void stage_write(char* buf, const float4* vreg,
                                            int lane) {
#pragma unroll
    for (int k = 0; k < 11; ++k)
        *(float4*)(buf + k * 1024 + lane * 16) = vreg[k];
}

__device__ __forceinline__ float sl1enc(const float l0, const float l1,
                                        const float l2, const float l3,
                                        const float4 pq,
                                        const float* __restrict__ tb4) {
    const float tx0 = tb4[0], ty0 = tb4[1], tx1 = tb4[2], ty1 = tb4[3];
    const float g0 = ((tx0 + tx1) * 0.5f - pq.x) / (VAR0_F * pq.z);
    const float g1 = ((ty0 + ty1) * 0.5f - pq.y) / (VAR0_F * pq.w);
    const float g2 = __logf((tx1 - tx0) / pq.z) / VAR1_F;
    const float g3 = __logf((ty1 - ty0) / pq.w) / VAR1_F;
    float s = 0.f, dd, ad;
    dd = l0 - g0; ad = fabsf(dd); s += (ad < 1.f) ? 0.5f * dd * dd : (ad - 0.5f);
    dd = l1 - g1; ad = fabsf(dd); s += (ad < 1.f) ? 0.5f * dd * dd : (ad - 0.5f);
    dd = l2 - g2; ad = fabsf(dd); s += (ad < 1.f) ? 0.5f * dd * dd : (ad - 0.5f);
    dd = l3 - g3; ad = fabsf(dd); s += (ad < 1.f) ? 0.5f * dd * dd : (ad - 0.5f);
    return s;
}

// ---------------------------------------------------------------- main fused
// R23: ONE MOVING WINDOW — flat (b,chunk) sequence, block s covers
// f = s, s+NBLK, ... so the whole chip streams a single contiguous ~20 MB
// window forward (m13's shape), vs 32 per-b windows before. All 1792 blocks
// co-resident (LDS 22.8 KB: candidate reduce moved LDS->shfl). Per-iteration
// flush: positives -> direct atomicAdd (rare); per-o keys -> atomicMax
// (fire-and-forget, 512 addresses).
__global__ __launch_bounds__(64) void k_main(
    const float* __restrict__ pred, const float* __restrict__ tboxes,
    const int* __restrict__ tlabels, const float* __restrict__ priors,
    float* __restrict__ lr, u64* __restrict__ gcand,
    float* __restrict__ accB) {
    __shared__ char smem[2][CB32];
    __shared__ float tbs[NO * 4];

    const int s0 = blockIdx.x;
    const int lane = threadIdx.x;
    const char* gpred = (const char*)pred;

    char* cur = smem[0];
    char* nxt = smem[1];

    const int rho = lane >> 1;
    const int h = lane & 1;
    const int c0 = rho & 3;
    const int Ab = 16 * (21 * rho + (rho >> 2));
    const int sbase = h ? 11 : 1;

    int f = s0;
    int fn = f + NBLK;
    {
        const int b0 = f / CHB32, ch0 = f - b0 * CHB32;
        float4 vreg[11];
        stage_load(vreg, gpred, b0, ch0 * 32, lane);
        stage_write(cur, vreg, lane);
    }

    while (f < FLAT_TOTAL) {
        const int b = f / CHB32;
        const int chunk = f - b * CHB32;
        const size_t bbase = (size_t)b * NP;
        tbs[lane] = tboxes[b * NO * 4 + lane];   // 1 wave: no barrier needed

        float4 vreg[11];
        const bool have_next = (fn < FLAT_TOTAL);
        if (have_next) {
            const int bn = fn / CHB32, chn = fn - bn * CHB32;
            stage_load(vreg, gpred, bn, chn * 32, lane);
        }

        const int r0 = chunk * 32;
        const int nrows = min(32, NP - r0);
        const int p = r0 + rho;
        const bool rok = (rho < nrows);

        float4 v[11];
#pragma unroll
        for (int k = 0; k < 11; ++k)
            v[k] = *(const float4*)(cur + Ab + 16 * (sbase + k));

        float vals[44];
#pragma unroll
        for (int k = 0; k < 11; ++k) {
            const float xs[4] = {v[k].x, v[k].y, v[k].z, v[k].w};
#pragma unroll
            for (int t = 0; t < 4; ++t) {
                bool okv;
                if (k == 0)
                    okv = h ? false : (t >= c0);
                else if (k == 10)
                    okv = h ? (t <= c0) : true;
                else
                    okv = true;
                vals[4 * k + t] = okv ? xs[t] : NEG_HUGE;
            }
        }
        float mA = vals[0], mB = vals[1];
#pragma unroll
        for (int j = 2; j < 44; j += 2) {
            mA = fmaxf(mA, vals[j]);
            mB = fmaxf(mB, vals[j + 1]);
        }
        float m = fmaxf(mA, mB);
        m = fmaxf(m, __shfl_xor(m, 1, 64));

        float sA = 0.f, sB = 0.f;
#pragma unroll
        for (int j = 0; j < 44; j += 2) {
            sA += __expf(vals[j] - m);
            sB += __expf(vals[j + 1] - m);
        }
        float ssum = sA + sB;
        ssum += __shfl_xor(ssum, 1, 64);
        const float lse = m + __logf(ssum);

        // fused IoU loop: row decision + per-o argmax byproduct (in regs)
        u64 ok[8];
#pragma unroll
        for (int j = 0; j < 8; ++j) ok[j] = 0ull;
        float bv = -1.f;
        int bi = 0;
        {
            const float4 pq = rok ? *((const float4*)priors + p)
                                  : make_float4(0.f, 0.f, 1.f, 1.f);
            const float prl = pq.x - pq.z * 0.5f, prt = pq.y - pq.w * 0.5f;
            const float prr2 = pq.x + pq.z * 0.5f, prb = pq.y + pq.w * 0.5f;
            const float parea = (prr2 - prl) * (prb - prt);
            const int obase = h * 8;
#pragma unroll
            for (int oj = 0; oj < 8; ++oj) {
                const int o = obase + oj;
                const float al = tbs[o * 4 + 0], at = tbs[o * 4 + 1];
                const float ar = tbs[o * 4 + 2], ab = tbs[o * 4 + 3];
                float iw = fminf(ar, prr2) - fmaxf(al, prl); iw = fmaxf(iw, 0.f);
                float ih = fminf(ab, prb) - fmaxf(at, prt); ih = fmaxf(ih, 0.f);
                const float inter = iw * ih;
                const float aarea = (ar - al) * (ab - at);
                const float iou = inter / (aarea + parea - inter);
                if (iou > bv) { bv = iou; bi = o; }
                if (rok)
                    ok[oj] = ((u64)__float_as_uint(iou) << 32) |
                             (u64)(0xFFFFFFFFu - (unsigned)p);
            }
            const float ov = __shfl_xor(bv, 1, 64);
            const int oi = __shfl_xor(bi, 1, 64);
            if (ov > bv || (ov == bv && oi < bi)) { bv = ov; bi = oi; }
        }

        if (h == 0 && rok) {
            const float bg = (c0 == 0) ? v[0].x : (c0 == 1) ? v[0].y
                           : (c0 == 2) ? v[0].z : v[0].w;
            const bool pos = (bv >= THRESH_F);   // unforced
            const int o = bi;
            lr[bbase + p] = pos ? 0.f : (lse - bg);
            if (pos) {   // rare: direct atomics (~60/b total)
                const float* rowp = (const float*)(cur + 340 * rho);
                const int lbl = tlabels[b * NO + o] + 1;
                const float4 pq = *((const float4*)priors + p);
                atomicAdd(&accB[b * 4 + 0],
                          sl1enc(rowp[0], rowp[1], rowp[2], rowp[3], pq,
                                 &tbs[o * 4]));
                atomicAdd(&accB[b * 4 + 1], lse - rowp[4 + lbl]);
                atomicAdd(&accB[b * 4 + 2], 1.f);
            }
        }

        // per-o candidate flush: shfl-reduce over rho (same-h lanes), then
        // lanes rho==0 (lane 0 and 1) fire 8 atomicMax each.
#pragma unroll
        for (int oj = 0; oj < 8; ++oj) {
            u64 m2 = ok[oj];
#pragma unroll
            for (int d = 2; d < 64; d <<= 1) {
                const u64 o2 = __shfl_xor(m2, d, 64);
                m2 = (o2 > m2) ? o2 : m2;
            }
            ok[oj] = m2;
        }
        if (rho == 0) {
#pragma unroll
            for (int oj = 0; oj < 8; ++oj)
                atomicMax(&gcand[(size_t)b * NO + h * 8 + oj], ok[oj]);
        }

        if (have_next)
            stage_write(nxt, vreg, lane);

        f = fn;
        fn += NBLK;
        char* tmp = cur; cur = nxt; nxt = tmp;
    }
}

// ---------------------------------------------------------------- select
// R22's fixup + 3-pass radix; reads gcand/accB directly.
__global__ __launch_bounds__(1024) void k_select(
    const float* __restrict__ pred, const float* __restrict__ tboxes,
    const int* __restrict__ tlabels, const float* __restrict__ priors,
    float* __restrict__ lrk, const u64* __restrict__ gcand,
    const float* __restrict__ accB, float* __restrict__ pout) {
    const int b = blockIdx.x;
    const int tid = threadIdx.x;
    const int lane = tid & 63;
    const int wid = tid >> 6;
    const int sub = lane & 15;

    __shared__ unsigned hist16[2048][16];  // 128 KiB
    __shared__ unsigned chist[2048];
    __shared__ int sh_bucket, sh_knew;
    __shared__ float wsum[16];
    __shared__ int wcnt[16];
    __shared__ float tbs[NO * 4];
    __shared__ int tl[NO];
    __shared__ int p16s[16];
    __shared__ float snp_f;
    __shared__ float fll, fce;
    __shared__ int fnp;

    if (tid < NO * 4) tbs[tid] = tboxes[b * NO * 4 + tid];
    if (tid >= 64 && tid < 64 + NO) tl[tid - 64] = tlabels[b * NO + tid - 64];
    if (tid >= 96 && tid < 96 + NO) {
        const u64 m = gcand[(size_t)b * NO + (tid - 96)];
        p16s[tid - 96] = (int)(0xFFFFFFFFu - (unsigned)(m & 0xFFFFFFFFull));
    }
    if (tid == 0) snp_f = accB[b * 4 + 2];
    __syncthreads();

    // fixup (wave 0; 4 lanes per forced slot)
    if (tid < 64) {
        const int g = lane >> 2, q = lane & 3;
        const int p = p16s[g];
        bool winner = true;
        for (int o2 = g + 1; o2 < NO; ++o2)
            if (p16s[o2] == p) winner = false;
        float dll = 0.f, dce = 0.f;
        int dnp = 0;
        if (winner) {
            const float* base = pred + (size_t)b * NP * ND;
            const int A = 21 * p + (p >> 2), c0 = p & 3;
            const float4* vp = (const float4*)base + A;
            float vals[24];
#pragma unroll
            for (int k = 0; k < 6; ++k) {
                const int s = q + 4 * k;
                const float4 f4 = vp[(s <= 21) ? s : 21];
                const float xs[4] = {f4.x, f4.y, f4.z, f4.w};
#pragma unroll
                for (int t = 0; t < 4; ++t) {
                    const int d = 4 * s + t - c0;
                    vals[4 * k + t] =
                        (s <= 21 && d >= 4 && d <= 84) ? xs[t] : NEG_HUGE;
                }
            }
            float mx = vals[0];
#pragma unroll
            for (int j = 1; j < 24; ++j) mx = fmaxf(mx, vals[j]);
            mx = fmaxf(mx, __shfl_xor(mx, 1, 64));
            mx = fmaxf(mx, __shfl_xor(mx, 2, 64));
            float es = 0.f;
#pragma unroll
            for (int j = 0; j < 24; ++j) es += __expf(vals[j] - mx);
            es += __shfl_xor(es, 1, 64);
            es += __shfl_xor(es, 2, 64);
            const float lse = mx + __logf(es);
            const float4 pq = *((const float4*)priors + p);
            const float prl = pq.x - pq.z * 0.5f, prt = pq.y - pq.w * 0.5f;
            const float prr2 = pq.x + pq.z * 0.5f, prb = pq.y + pq.w * 0.5f;
            const float parea = (prr2 - prl) * (prb - prt);
            float bv = -1.f;
            int bi = 0;
#pragma unroll
            for (int jj = 0; jj < 4; ++jj) {
                const int o2 = q * 4 + jj;
                const float al = tbs[o2 * 4 + 0], at = tbs[o2 * 4 + 1];
                const float ar = tbs[o2 * 4 + 2], ab = tbs[o2 * 4 + 3];
                float iw = fminf(ar, prr2) - fmaxf(al, prl); iw = fmaxf(iw, 0.f);
                float ih = fminf(ab, prb) - fmaxf(at, prt); ih = fmaxf(ih, 0.f);
                const float inter = iw * ih;
                const float aarea = (ar - al) * (ab - at);
                const float iou = inter / (aarea + parea - inter);
                if (iou > bv) { bv = iou; bi = o2; }
            }
#pragma unroll
            for (int d = 1; d <= 2; d <<= 1) {
                const float ov = __shfl_xor(bv, d, 64);
                const int oi = __shfl_xor(bi, d, 64);
                if (ov > bv || (ov == bv && oi < bi)) { bv = ov; bi = oi; }
            }
            if (q == 0) {
                const float* rowp = base + (size_t)p * ND;
                const float l0 = rowp[0], l1 = rowp[1];
                const float l2 = rowp[2], l3 = rowp[3];
                const bool was_pos = (bv >= THRESH_F);
                const float ce_f = lse - rowp[4 + tl[g] + 1];
                const float ll_f = sl1enc(l0, l1, l2, l3, pq, &tbs[g * 4]);
                if (was_pos) {
                    const float ce_nf = lse - rowp[4 + tl[bi] + 1];
                    const float ll_nf = sl1enc(l0, l1, l2, l3, pq, &tbs[bi * 4]);
                    dll = ll_f - ll_nf;
                    dce = ce_f - ce_nf;
                } else {
                    dll = ll_f;
                    dce = ce_f;
                    dnp = 1;
                    lrk[(size_t)b * NP + p] = 0.f;
                }
            }
        }
        for (int d2 = 1; d2 < 64; d2 <<= 1) {
            dll += __shfl_xor(dll, d2, 64);
            dce += __shfl_xor(dce, d2, 64);
            dnp += __shfl_xor(dnp, d2, 64);
        }
        if (lane == 0) { fll = dll; fce = dce; fnp = dnp; }
    }
    __threadfence_block();
    __syncthreads();

    const int npb = (int)(snp_f + 0.5f) + fnp;

    const float4* row4 = (const float4*)(lrk + (size_t)b * NP);
    float4 cch[7];
    bool cvz[7];
#pragma unroll
    for (int j = 0; j < 7; ++j) {
        const int i = tid + j * 1024;
        cvz[j] = (i < NP / 4);
        cch[j] = cvz[j] ? row4[i] : make_float4(0.f, 0.f, 0.f, 0.f);
    }

    const int K0 = min(npb * NEGPOS_I, NP);
    int k = K0;
    unsigned prefix = 0;
    const int shifts[3] = {21, 10, 0};
    const unsigned masks[3] = {0u, 0xFFE00000u, 0xFFFFFC00u};

    for (int pass = 0; pass < 3; ++pass) {
        const int shift = shifts[pass];
        const unsigned mask_hi = masks[pass];
        {
            uint4* hz = (uint4*)hist16;
            for (int j = tid; j < 2048 * 4; j += 1024)
                hz[j] = make_uint4(0u, 0u, 0u, 0u);
        }
        __syncthreads();
#pragma unroll
        for (int j = 0; j < 7; ++j) {
            if (cvz[j]) {
                const float4 v4 = cch[j];
#pragma unroll
                for (int c = 0; c < 4; ++c) {
                    const float fvl = (c == 0) ? v4.x : (c == 1) ? v4.y
                                    : (c == 2) ? v4.z : v4.w;
                    const unsigned v = __float_as_uint(fvl);
                    if ((v & mask_hi) == (prefix & mask_hi))
                        atomicAdd(&hist16[(v >> shift) & 2047u][sub], 1u);
                }
            }
        }
        __syncthreads();
        for (int j = tid; j < 2048; j += 1024) {
            const uint4* hp = (const uint4*)&hist16[j][0];
            const uint4 a = hp[0], b4 = hp[1], c4 = hp[2], d4 = hp[3];
            chist[j] = a.x + a.y + a.z + a.w + b4.x + b4.y + b4.z + b4.w +
                       c4.x + c4.y + c4.z + c4.w + d4.x + d4.y + d4.z + d4.w;
        }
        __syncthreads();
        if (tid < 64) {
            unsigned g = 0;
            for (int j = 0; j < 32; ++j) g += chist[lane * 32 + j];
            unsigned T = g;
            for (int d = 1; d < 64; d <<= 1) {
                const unsigned t = __shfl_down(T, d, 64);
                if (lane + d < 64) T += t;
            }
            const unsigned E = T - g;
            const bool hit = (E < (unsigned)k) && ((unsigned)k <= T);
            const unsigned long long msk = __ballot(hit);
            const int wl = __ffsll(msk) - 1;
            if (lane == wl) {
                unsigned cum = E;
                int bsel = lane * 32, kn = k;
                for (int j = 31; j >= 0; --j) {
                    const unsigned c = chist[lane * 32 + j];
                    if (cum + c >= (unsigned)k) {
                        bsel = lane * 32 + j;
                        kn = k - (int)cum;
                        break;
                    }
                    cum += c;
                }
                sh_bucket = bsel;
                sh_knew = kn;
            }
        }
        __syncthreads();
        prefix |= ((unsigned)sh_bucket) << shift;
        k = sh_knew;
        __syncthreads();
    }
    const float T = __uint_as_float(prefix);

    float msum = 0.f;
    int mcnt = 0;
#pragma unroll
    for (int j = 0; j < 7; ++j) {
        if (cvz[j]) {
            const float4 v4 = cch[j];
#pragma unroll
            for (int c = 0; c < 4; ++c) {
                const float fvl = (c == 0) ? v4.x : (c == 1) ? v4.y
                                : (c == 2) ? v4.z : v4.w;
                if (__float_as_uint(fvl) > prefix) { msum += fvl; mcnt++; }
            }
        }
    }
    for (int s = 32; s > 0; s >>= 1) {
        msum += __shfl_down(msum, s, 64);
        mcnt += __shfl_down(mcnt, s, 64);
    }
    if (lane == 0) { wsum[wid] = msum; wcnt[wid] = mcnt; }
    __syncthreads();
    if (tid == 0) {
        float tot = 0.f;
        int cnt = 0;
        for (int w = 0; w < 16; ++w) { tot += wsum[w]; cnt += wcnt[w]; }
        const float negsum = tot + (float)(K0 - cnt) * T;
        pout[b * 4 + 0] = accB[b * 4 + 0] + fll;
        pout[b * 4 + 1] = accB[b * 4 + 1] + fce + negsum;
        pout[b * 4 + 2] = (float)npb;
    }
}

// ---------------------------------------------------------------- final
__global__ void k_final(const float* __restrict__ pout,
                        float* __restrict__ out) {
    if (threadIdx.x == 0 && blockIdx.x == 0) {
        float a0 = 0.f, a1 = 0.f, n = 0.f;
        for (int b = 0; b < NB; ++b) {
            a0 += pout[b * 4 + 0];
            a1 += pout[b * 4 + 1];
            n += pout[b * 4 + 2];
        }
        out[0] = a0 / n;
        out[1] = a1 / n;
    }
}

extern "C" void kernel_launch(void* const* d_in, const int* in_sizes, int n_in,
                              void* d_out, int out_size, void* d_ws, size_t ws_size,
                              hipStream_t stream) {
    const float* pred   = (const float*)d_in[0];
    const float* tboxes = (const float*)d_in[1];
    const int*   tlabels = (const int*)d_in[2];
    const float* priors = (const float*)d_in[3];
    float* out = (float*)d_out;

    char* w = (char*)d_ws;
    float* lrk  = (float*)w;                         // 4*BPCNT
    char*  w2 = w + 4ull * BPCNT;
    u64*   gcand = (u64*)w2;                         // NB*NO u64 = 4096 B
    float* accB = (float*)(w2 + 4096);               // NB*4 f32 = 512 B
    float* pout = (float*)(w2 + 8192);               // NB*4 f32

    hipMemsetAsync(w2, 0, 4608, stream);             // gcand + accB = 0
    k_main<<<dim3(NBLK), dim3(64), 0, stream>>>(
        pred, tboxes, tlabels, priors, lrk, gcand, accB);
    k_select<<<dim3(NB), dim3(1024), 0, stream>>>(
        pred, tboxes, tlabels, priors, lrk, gcand, accB, pout);
    k_final<<<dim3(1), dim3(1), 0, stream>>>(pout, out);
}

// Round 24
// 115.690 us; speedup vs baseline: 3.2284x; 3.2284x over previous
//
#include <hip/hip_runtime.h>
#include <math.h>

#define NB 32
#define NP 24656
#define NO 16
#define NC 81
#define ND 85   // 4 + NC
#define THRESH_F 0.5f
#define NEGPOS_I 3
#define VAR0_F 0.1f
#define VAR1_F 0.2f
#define NEG_HUGE -1e30f

#define BPCNT (NB * NP)
#define CHB32 771        // 32-row chunks per batch row = ceil(NP/32)
#define SPB2 56          // k_main blocks per batch row
#define CB32 11264       // staged bytes per chunk = 11 x 1024

typedef unsigned long long u64;

// ---------------------------------------------------------------- stage (reg)
__device__ __forceinline__ void stage_load(float4* vreg,
                                           const char* __restrict__ gpred,
                                           int b, int r0, int lane) {
    const size_t off = ((size_t)b * NP + r0) * 340ull;
    const char* g = gpred + off;
    const bool unsafe = (b == NB - 1) && (r0 + 34 > NP);
    if (!unsafe) {
#pragma unroll
        for (int k = 0; k < 11; ++k)
            vreg[k] = *(const float4*)(g + k * 1024 + lane * 16);
    } else {
        const int nf4 = (NP - r0) * ND / 4;
        const float4* gs = (const float4*)g;
#pragma unroll
        for (int k = 0; k < 11; ++k) {
            const int idx = k * 64 + lane;
            vreg[k] = (idx < nf4) ? gs[idx]
                                  : make_float4(0.f, 0.f, 0.f, 0.f);
        }
    }
}

__device__ __forceinline__ void stage_write(char* buf, const float4* vreg,
                                            int lane) {
#pragma unroll
    for (int k = 0; k < 11; ++k)
        *(float4*)(buf + k * 1024 + lane * 16) = vreg[k];
}

__device__ __forceinline__ float sl1enc(const float l0, const float l1,
                                        const float l2, const float l3,
                                        const float4 pq,
                                        const float* __restrict__ tb4) {
    const float tx0 = tb4[0], ty0 = tb4[1], tx1 = tb4[2], ty1 = tb4[3];
    const float g0 = ((tx0 + tx1) * 0.5f - pq.x) / (VAR0_F * pq.z);
    const float g1 = ((ty0 + ty1) * 0.5f - pq.y) / (VAR0_F * pq.w);
    const float g2 = __logf((tx1 - tx0) / pq.z) / VAR1_F;
    const float g3 = __logf((ty1 - ty0) / pq.w) / VAR1_F;
    float s = 0.f, dd, ad;
    dd = l0 - g0; ad = fabsf(dd); s += (ad < 1.f) ? 0.5f * dd * dd : (ad - 0.5f);
    dd = l1 - g1; ad = fabsf(dd); s += (ad < 1.f) ? 0.5f * dd * dd : (ad - 0.5f);
    dd = l2 - g2; ad = fabsf(dd); s += (ad < 1.f) ? 0.5f * dd * dd : (ad - 0.5f);
    dd = l3 - g3; ad = fabsf(dd); s += (ad < 1.f) ? 0.5f * dd * dd : (ad - 0.5f);
    return s;
}

// ---------------------------------------------------------------- main fused
// R22 structure (best measured: 105.0 us). Per-b windows; per-block partials
// via plain stores; per-o argmax byproduct reduced via LDS once per block.
__global__ __launch_bounds__(64) void k_main(
    const float* __restrict__ pred, const float* __restrict__ tboxes,
    const int* __restrict__ tlabels, const float* __restrict__ priors,
    float* __restrict__ lr, u64* __restrict__ bcand,
    float* __restrict__ pll, float* __restrict__ pce,
    float* __restrict__ pnp) {
    __shared__ char smem[2][CB32];
    __shared__ float tbs[NO * 4];
    __shared__ u64 kk[16][32];
    __shared__ u64 pb2[16][4];

    const int b = blockIdx.y;
    const int span = blockIdx.x;
    const int lane = threadIdx.x;
    const size_t bbase = (size_t)b * NP;
    const char* gpred = (const char*)pred;

    char* cur = smem[0];
    char* nxt = smem[1];

    const int rho = lane >> 1;
    const int h = lane & 1;
    const int c0 = rho & 3;
    const int Ab = 16 * (21 * rho + (rho >> 2));
    const int sbase = h ? 11 : 1;

    tbs[lane] = tboxes[b * NO * 4 + lane];

    u64 ok[8];
#pragma unroll
    for (int j = 0; j < 8; ++j) ok[j] = 0ull;

    float my_ll = 0.f, my_ce = 0.f;
    int my_np = 0;

    int chunk = span;
    int next_chunk = chunk + SPB2;
    {
        float4 vreg[11];
        stage_load(vreg, gpred, b, chunk * 32, lane);
        stage_write(cur, vreg, lane);
    }

    while (chunk < CHB32) {
        float4 vreg[11];
        const bool have_next = (next_chunk < CHB32);
        if (have_next)
            stage_load(vreg, gpred, b, next_chunk * 32, lane);

        const int r0 = chunk * 32;
        const int nrows = min(32, NP - r0);
        const int p = r0 + rho;
        const bool rok = (rho < nrows);

        float4 v[11];
#pragma unroll
        for (int k = 0; k < 11; ++k)
            v[k] = *(const float4*)(cur + Ab + 16 * (sbase + k));

        float vals[44];
#pragma unroll
        for (int k = 0; k < 11; ++k) {
            const float xs[4] = {v[k].x, v[k].y, v[k].z, v[k].w};
#pragma unroll
            for (int t = 0; t < 4; ++t) {
                bool okv;
                if (k == 0)
                    okv = h ? false : (t >= c0);
                else if (k == 10)
                    okv = h ? (t <= c0) : true;
                else
                    okv = true;
                vals[4 * k + t] = okv ? xs[t] : NEG_HUGE;
            }
        }
        float mA = vals[0], mB = vals[1];
#pragma unroll
        for (int j = 2; j < 44; j += 2) {
            mA = fmaxf(mA, vals[j]);
            mB = fmaxf(mB, vals[j + 1]);
        }
        float m = fmaxf(mA, mB);
        m = fmaxf(m, __shfl_xor(m, 1, 64));

        float sA = 0.f, sB = 0.f;
#pragma unroll
        for (int j = 0; j < 44; j += 2) {
            sA += __expf(vals[j] - m);
            sB += __expf(vals[j + 1] - m);
        }
        float ssum = sA + sB;
        ssum += __shfl_xor(ssum, 1, 64);
        const float lse = m + __logf(ssum);

        // fused IoU loop: row decision + per-o argmax byproduct
        float bv = -1.f;
        int bi = 0;
        {
            const float4 pq = rok ? *((const float4*)priors + p)
                                  : make_float4(0.f, 0.f, 1.f, 1.f);
            const float prl = pq.x - pq.z * 0.5f, prt = pq.y - pq.w * 0.5f;
            const float prr2 = pq.x + pq.z * 0.5f, prb = pq.y + pq.w * 0.5f;
            const float parea = (prr2 - prl) * (prb - prt);
            const int obase = h * 8;
#pragma unroll
            for (int oj = 0; oj < 8; ++oj) {
                const int o = obase + oj;
                const float al = tbs[o * 4 + 0], at = tbs[o * 4 + 1];
                const float ar = tbs[o * 4 + 2], ab = tbs[o * 4 + 3];
                float iw = fminf(ar, prr2) - fmaxf(al, prl); iw = fmaxf(iw, 0.f);
                float ih = fminf(ab, prb) - fmaxf(at, prt); ih = fmaxf(ih, 0.f);
                const float inter = iw * ih;
                const float aarea = (ar - al) * (ab - at);
                const float iou = inter / (aarea + parea - inter);
                if (iou > bv) { bv = iou; bi = o; }
                if (rok) {
                    const u64 key = ((u64)__float_as_uint(iou) << 32) |
                                    (u64)(0xFFFFFFFFu - (unsigned)p);
                    ok[oj] = (key > ok[oj]) ? key : ok[oj];
                }
            }
            const float ov = __shfl_xor(bv, 1, 64);
            const int oi = __shfl_xor(bi, 1, 64);
            if (ov > bv || (ov == bv && oi < bi)) { bv = ov; bi = oi; }
        }

        if (h == 0 && rok) {
            const float bg = (c0 == 0) ? v[0].x : (c0 == 1) ? v[0].y
                           : (c0 == 2) ? v[0].z : v[0].w;
            const bool pos = (bv >= THRESH_F);     // UNFORCED
            const int o = bi;
            lr[bbase + p] = pos ? 0.f : (lse - bg);
            if (pos) {
                my_np += 1;
                const float* rowp = (const float*)(cur + 340 * rho);
                const int lbl = tlabels[b * NO + o] + 1;
                my_ce += lse - rowp[4 + lbl];
                const float4 pq = *((const float4*)priors + p);
                my_ll += sl1enc(rowp[0], rowp[1], rowp[2], rowp[3], pq,
                                &tbs[o * 4]);
            }
        }

        if (have_next)
            stage_write(nxt, vreg, lane);

        chunk = next_chunk;
        next_chunk += SPB2;
        char* tmp = cur; cur = nxt; nxt = tmp;
    }

    // per-block partial reduce (plain stores -> no init/atomics needed)
    for (int d2 = 1; d2 < 64; d2 <<= 1) {
        my_ll += __shfl_xor(my_ll, d2, 64);
        my_ce += __shfl_xor(my_ce, d2, 64);
        my_np += __shfl_xor(my_np, d2, 64);
    }
    if (lane == 0) {
        pll[b * SPB2 + span] = my_ll;
        pce[b * SPB2 + span] = my_ce;
        pnp[b * SPB2 + span] = (float)my_np;
    }

    // per-o block candidate reduce: kk[16][32] -> pb2[16][4] -> bcand
#pragma unroll
    for (int j = 0; j < 8; ++j) kk[h * 8 + j][rho] = ok[j];
    __syncthreads();
    {
        const int o = lane >> 2, seg = lane & 3;
        u64 m2 = 0ull;
#pragma unroll
        for (int i = 0; i < 8; ++i) {
            const u64 vv = kk[o][seg * 8 + i];
            m2 = (vv > m2) ? vv : m2;
        }
        pb2[o][seg] = m2;
    }
    __syncthreads();
    if (lane < NO) {
        u64 m2 = pb2[lane][0];
#pragma unroll
        for (int i = 1; i < 4; ++i) {
            const u64 vv = pb2[lane][i];
            m2 = (vv > m2) ? vv : m2;
        }
        bcand[((size_t)b * NO + lane) * SPB2 + span] = m2;
    }
}

// ---------------------------------------------------------------- select
// R22 fixup + 3-pass radix; k_final MERGED (done-counter, init by memset).
__global__ __launch_bounds__(1024) void k_select(
    const float* __restrict__ pred, const float* __restrict__ tboxes,
    const int* __restrict__ tlabels, const float* __restrict__ priors,
    float* __restrict__ lrk, const u64* __restrict__ bcand,
    const float* __restrict__ pll, const float* __restrict__ pce,
    const float* __restrict__ pnp, float* __restrict__ pout,
    int* __restrict__ done, float* __restrict__ out) {
    const int b = blockIdx.x;
    const int tid = threadIdx.x;
    const int lane = tid & 63;
    const int wid = tid >> 6;
    const int sub = lane & 15;

    __shared__ unsigned hist16[2048][16];  // 128 KiB
    __shared__ unsigned chist[2048];
    __shared__ int sh_bucket, sh_knew;
    __shared__ float wsum[16];
    __shared__ int wcnt[16];
    __shared__ float tbs[NO * 4];
    __shared__ int tl[NO];
    __shared__ u64 pbq[16][4];
    __shared__ int p16s[16];
    __shared__ float sparts[56 * 3];
    __shared__ float sll, sce, snp_f;
    __shared__ float fll, fce;
    __shared__ int fnp;

    // phase A: loads + candidate partial reduce + partial-sum staging
    if (tid < NO * 4) tbs[tid] = tboxes[b * NO * 4 + tid];
    if (tid >= 128 && tid < 128 + NO) tl[tid - 128] = tlabels[b * NO + tid - 128];
    if (tid < 64) {
        const int o = tid & 15, grp = tid >> 4;
        const u64* c = bcand + ((size_t)b * NO + o) * SPB2 + grp * 14;
        u64 m = 0ull;
        for (int i = 0; i < 14; ++i) {
            const u64 v = c[i];
            m = (v > m) ? v : m;
        }
        pbq[o][grp] = m;
    }
    if (tid >= 64 && tid < 120) {
        const int l = tid - 64;
        sparts[l * 3 + 0] = pll[b * SPB2 + l];
        sparts[l * 3 + 1] = pce[b * SPB2 + l];
        sparts[l * 3 + 2] = pnp[b * SPB2 + l];
    }
    __syncthreads();
    // phase B: finalize p16s + serial partial sums
    if (tid < NO) {
        u64 m = pbq[tid][0];
#pragma unroll
        for (int i = 1; i < 4; ++i) {
            const u64 v = pbq[tid][i];
            m = (v > m) ? v : m;
        }
        p16s[tid] = (int)(0xFFFFFFFFu - (unsigned)(m & 0xFFFFFFFFull));
    }
    if (tid == 32) {
        float a = 0.f, c = 0.f, n = 0.f;
        for (int l = 0; l < 56; ++l) {
            a += sparts[l * 3 + 0];
            c += sparts[l * 3 + 1];
            n += sparts[l * 3 + 2];
        }
        sll = a; sce = c; snp_f = n;
    }
    __syncthreads();
    // phase C: fixup (wave 0; 4 lanes per forced slot)
    if (tid < 64) {
        const int g = lane >> 2, q = lane & 3;
        const int p = p16s[g];
        bool winner = true;
        for (int o2 = g + 1; o2 < NO; ++o2)
            if (p16s[o2] == p) winner = false;
        float dll = 0.f, dce = 0.f;
        int dnp = 0;
        if (winner) {
            const float* base = pred + (size_t)b * NP * ND;
            const int A = 21 * p + (p >> 2), c0 = p & 3;
            const float4* vp = (const float4*)base + A;
            float vals[24];
#pragma unroll
            for (int k = 0; k < 6; ++k) {
                const int s = q + 4 * k;
                const float4 f4 = vp[(s <= 21) ? s : 21];
                const float xs[4] = {f4.x, f4.y, f4.z, f4.w};
#pragma unroll
                for (int t = 0; t < 4; ++t) {
                    const int d = 4 * s + t - c0;
                    vals[4 * k + t] =
                        (s <= 21 && d >= 4 && d <= 84) ? xs[t] : NEG_HUGE;
                }
            }
            float mx = vals[0];
#pragma unroll
            for (int j = 1; j < 24; ++j) mx = fmaxf(mx, vals[j]);
            mx = fmaxf(mx, __shfl_xor(mx, 1, 64));
            mx = fmaxf(mx, __shfl_xor(mx, 2, 64));
            float es = 0.f;
#pragma unroll
            for (int j = 0; j < 24; ++j) es += __expf(vals[j] - mx);
            es += __shfl_xor(es, 1, 64);
            es += __shfl_xor(es, 2, 64);
            const float lse = mx + __logf(es);
            const float4 pq = *((const float4*)priors + p);
            const float prl = pq.x - pq.z * 0.5f, prt = pq.y - pq.w * 0.5f;
            const float prr2 = pq.x + pq.z * 0.5f, prb = pq.y + pq.w * 0.5f;
            const float parea = (prr2 - prl) * (prb - prt);
            float bv = -1.f;
            int bi = 0;
#pragma unroll
            for (int jj = 0; jj < 4; ++jj) {
                const int o2 = q * 4 + jj;
                const float al = tbs[o2 * 4 + 0], at = tbs[o2 * 4 + 1];
                const float ar = tbs[o2 * 4 + 2], ab = tbs[o2 * 4 + 3];
                float iw = fminf(ar, prr2) - fmaxf(al, prl); iw = fmaxf(iw, 0.f);
                float ih = fminf(ab, prb) - fmaxf(at, prt); ih = fmaxf(ih, 0.f);
                const float inter = iw * ih;
                const float aarea = (ar - al) * (ab - at);
                const float iou = inter / (aarea + parea - inter);
                if (iou > bv) { bv = iou; bi = o2; }
            }
#pragma unroll
            for (int d = 1; d <= 2; d <<= 1) {
                const float ov = __shfl_xor(bv, d, 64);
                const int oi = __shfl_xor(bi, d, 64);
                if (ov > bv || (ov == bv && oi < bi)) { bv = ov; bi = oi; }
            }
            if (q == 0) {
                const float* rowp = base + (size_t)p * ND;
                const float l0 = rowp[0], l1 = rowp[1];
                const float l2 = rowp[2], l3 = rowp[3];
                const bool was_pos = (bv >= THRESH_F);
                const float ce_f = lse - rowp[4 + tl[g] + 1];
                const float ll_f = sl1enc(l0, l1, l2, l3, pq, &tbs[g * 4]);
                if (was_pos) {
                    const float ce_nf = lse - rowp[4 + tl[bi] + 1];
                    const float ll_nf = sl1enc(l0, l1, l2, l3, pq, &tbs[bi * 4]);
                    dll = ll_f - ll_nf;
                    dce = ce_f - ce_nf;
                } else {
                    dll = ll_f;
                    dce = ce_f;
                    dnp = 1;
                    lrk[(size_t)b * NP + p] = 0.f;   // forced row leaves neg set
                }
            }
        }
        for (int d2 = 1; d2 < 64; d2 <<= 1) {
            dll += __shfl_xor(dll, d2, 64);
            dce += __shfl_xor(dce, d2, 64);
            dnp += __shfl_xor(dnp, d2, 64);
        }
        if (lane == 0) { fll = dll; fce = dce; fnp = dnp; }
    }
    __threadfence_block();
    __syncthreads();

    const float llb = sll + fll;
    const float ceb = sce + fce;
    const int npb = (int)(snp_f + 0.5f) + fnp;

    // phase D: register-cache + 3-pass radix (post-fix lrk)
    const float4* row4 = (const float4*)(lrk + (size_t)b * NP);
    float4 cch[7];
    bool cvz[7];
#pragma unroll
    for (int j = 0; j < 7; ++j) {
        const int i = tid + j * 1024;
        cvz[j] = (i < NP / 4);
        cch[j] = cvz[j] ? row4[i] : make_float4(0.f, 0.f, 0.f, 0.f);
    }

    const int K0 = min(npb * NEGPOS_I, NP);
    int k = K0;
    unsigned prefix = 0;
    const int shifts[3] = {21, 10, 0};
    const unsigned masks[3] = {0u, 0xFFE00000u, 0xFFFFFC00u};

    for (int pass = 0; pass < 3; ++pass) {
        const int shift = shifts[pass];
        const unsigned mask_hi = masks[pass];
        {
            uint4* hz = (uint4*)hist16;
            for (int j = tid; j < 2048 * 4; j += 1024)
                hz[j] = make_uint4(0u, 0u, 0u, 0u);
        }
        __syncthreads();
#pragma unroll
        for (int j = 0; j < 7; ++j) {
            if (cvz[j]) {
                const float4 v4 = cch[j];
#pragma unroll
                for (int c = 0; c < 4; ++c) {
                    const float f = (c == 0) ? v4.x : (c == 1) ? v4.y
                                  : (c == 2) ? v4.z : v4.w;
                    const unsigned v = __float_as_uint(f);
                    if ((v & mask_hi) == (prefix & mask_hi))
                        atomicAdd(&hist16[(v >> shift) & 2047u][sub], 1u);
                }
            }
        }
        __syncthreads();
        for (int j = tid; j < 2048; j += 1024) {
            const uint4* hp = (const uint4*)&hist16[j][0];
            const uint4 a = hp[0], b4 = hp[1], c4 = hp[2], d4 = hp[3];
            chist[j] = a.x + a.y + a.z + a.w + b4.x + b4.y + b4.z + b4.w +
                       c4.x + c4.y + c4.z + c4.w + d4.x + d4.y + d4.z + d4.w;
        }
        __syncthreads();
        if (tid < 64) {
            unsigned g = 0;
            for (int j = 0; j < 32; ++j) g += chist[lane * 32 + j];
            unsigned T = g;
            for (int d = 1; d < 64; d <<= 1) {
                const unsigned t = __shfl_down(T, d, 64);
                if (lane + d < 64) T += t;
            }
            const unsigned E = T - g;
            const bool hit = (E < (unsigned)k) && ((unsigned)k <= T);
            const unsigned long long msk = __ballot(hit);
            const int wl = __ffsll(msk) - 1;
            if (lane == wl) {
                unsigned cum = E;
                int bsel = lane * 32, kn = k;
                for (int j = 31; j >= 0; --j) {
                    const unsigned c = chist[lane * 32 + j];
                    if (cum + c >= (unsigned)k) {
                        bsel = lane * 32 + j;
                        kn = k - (int)cum;
                        break;
                    }
                    cum += c;
                }
                sh_bucket = bsel;
                sh_knew = kn;
            }
        }
        __syncthreads();
        prefix |= ((unsigned)sh_bucket) << shift;
        k = sh_knew;
        __syncthreads();
    }
    const float T = __uint_as_float(prefix);

    float msum = 0.f;
    int mcnt = 0;
#pragma unroll
    for (int j = 0; j < 7; ++j) {
        if (cvz[j]) {
            const float4 v4 = cch[j];
#pragma unroll
            for (int c = 0; c < 4; ++c) {
                const float f = (c == 0) ? v4.x : (c == 1) ? v4.y
                              : (c == 2) ? v4.z : v4.w;
                if (__float_as_uint(f) > prefix) { msum += f; mcnt++; }
            }
        }
    }
    for (int s = 32; s > 0; s >>= 1) {
        msum += __shfl_down(msum, s, 64);
        mcnt += __shfl_down(mcnt, s, 64);
    }
    if (lane == 0) { wsum[wid] = msum; wcnt[wid] = mcnt; }
    __syncthreads();
    if (tid == 0) {
        float tot = 0.f;
        int cnt = 0;
        for (int w = 0; w < 16; ++w) { tot += wsum[w]; cnt += wcnt[w]; }
        const float negsum = tot + (float)(K0 - cnt) * T;
        pout[b * 4 + 0] = llb;
        pout[b * 4 + 1] = ceb + negsum;
        pout[b * 4 + 2] = (float)npb;
        __threadfence();
        if (atomicAdd(done, 1) == NB - 1) {   // merged k_final
            volatile const float* vp2 = pout;
            float a0 = 0.f, a1 = 0.f, n = 0.f;
            for (int bb = 0; bb < NB; ++bb) {
                a0 += vp2[bb * 4 + 0];
                a1 += vp2[bb * 4 + 1];
                n += vp2[bb * 4 + 2];
            }
            out[0] = a0 / n;
            out[1] = a1 / n;
        }
    }
}

extern "C" void kernel_launch(void* const* d_in, const int* in_sizes, int n_in,
                              void* d_out, int out_size, void* d_ws, size_t ws_size,
                              hipStream_t stream) {
    const float* pred   = (const float*)d_in[0];
    const float* tboxes = (const float*)d_in[1];
    const int*   tlabels = (const int*)d_in[2];
    const float* priors = (const float*)d_in[3];
    float* out = (float*)d_out;

    char* w = (char*)d_ws;
    float* lrk  = (float*)w;                                  // 4*BPCNT
    u64*   bcand = (u64*)(w + 4ull * BPCNT);                  // NB*NO*SPB2 u64
    char*  w2 = w + 4ull * BPCNT + 8ull * NB * NO * SPB2;
    float* pll = (float*)w2;                                  // NB*SPB2
    float* pce = (float*)(w2 + 4ull * NB * SPB2);
    float* pnp = (float*)(w2 + 8ull * NB * SPB2);
    float* pout = (float*)(w2 + 12ull * NB * SPB2);           // NB*4
    int*   done = (int*)(w2 + 12ull * NB * SPB2 + 512);       // 1 i32

    hipMemsetAsync(done, 0, 4, stream);
    k_main<<<dim3(SPB2, NB), dim3(64), 0, stream>>>(
        pred, tboxes, tlabels, priors, lrk, bcand, pll, pce, pnp);
    k_select<<<dim3(NB), dim3(1024), 0, stream>>>(
        pred, tboxes, tlabels, priors, lrk, bcand, pll, pce, pnp, pout,
        done, out);
}

// Round 25
// 104.478 us; speedup vs baseline: 3.5748x; 1.1073x over previous
//
#include <hip/hip_runtime.h>
#include <math.h>

#define NB 32
#define NP 24656
#define NO 16
#define NC 81
#define ND 85   // 4 + NC
#define THRESH_F 0.5f
#define NEGPOS_I 3
#define VAR0_F 0.1f
#define VAR1_F 0.2f
#define NEG_HUGE -1e30f

#define BPCNT (NB * NP)
#define CHB32 771        // 32-row chunks per batch row = ceil(NP/32)
#define SPB2 56          // k_main blocks per batch row
#define CB32 11264       // staged bytes per chunk = 11 x 1024

typedef unsigned long long u64;

// ---------------------------------------------------------------- stage (reg)
__device__ __forceinline__ void stage_load(float4* vreg,
                                           const char* __restrict__ gpred,
                                           int b, int r0, int lane) {
    const size_t off = ((size_t)b * NP + r0) * 340ull;
    const char* g = gpred + off;
    const bool unsafe = (b == NB - 1) && (r0 + 34 > NP);
    if (!unsafe) {
#pragma unroll
        for (int k = 0; k < 11; ++k)
            vreg[k] = *(const float4*)(g + k * 1024 + lane * 16);
    } else {
        const int nf4 = (NP - r0) * ND / 4;
        const float4* gs = (const float4*)g;
#pragma unroll
        for (int k = 0; k < 11; ++k) {
            const int idx = k * 64 + lane;
            vreg[k] = (idx < nf4) ? gs[idx]
                                  : make_float4(0.f, 0.f, 0.f, 0.f);
        }
    }
}

__device__ __forceinline__ void stage_write(char* buf, const float4* vreg,
                                            int lane) {
#pragma unroll
    for (int k = 0; k < 11; ++k)
        *(float4*)(buf + k * 1024 + lane * 16) = vreg[k];
}

__device__ __forceinline__ float sl1enc(const float l0, const float l1,
                                        const float l2, const float l3,
                                        const float4 pq,
                                        const float* __restrict__ tb4) {
    const float tx0 = tb4[0], ty0 = tb4[1], tx1 = tb4[2], ty1 = tb4[3];
    const float g0 = ((tx0 + tx1) * 0.5f - pq.x) / (VAR0_F * pq.z);
    const float g1 = ((ty0 + ty1) * 0.5f - pq.y) / (VAR0_F * pq.w);
    const float g2 = __logf((tx1 - tx0) / pq.z) / VAR1_F;
    const float g3 = __logf((ty1 - ty0) / pq.w) / VAR1_F;
    float s = 0.f, dd, ad;
    dd = l0 - g0; ad = fabsf(dd); s += (ad < 1.f) ? 0.5f * dd * dd : (ad - 0.5f);
    dd = l1 - g1; ad = fabsf(dd); s += (ad < 1.f) ? 0.5f * dd * dd : (ad - 0.5f);
    dd = l2 - g2; ad = fabsf(dd); s += (ad < 1.f) ? 0.5f * dd * dd : (ad - 0.5f);
    dd = l3 - g3; ad = fabsf(dd); s += (ad < 1.f) ? 0.5f * dd * dd : (ad - 0.5f);
    return s;
}

// ---------------------------------------------------------------- main fused
// R22 structure (best measured: 105.0 us). Per-b windows; per-block partials
// via plain stores; per-o argmax byproduct reduced via LDS once per block.
__global__ __launch_bounds__(64) void k_main(
    const float* __restrict__ pred, const float* __restrict__ tboxes,
    const int* __restrict__ tlabels, const float* __restrict__ priors,
    float* __restrict__ lr, u64* __restrict__ bcand,
    float* __restrict__ pll, float* __restrict__ pce,
    float* __restrict__ pnp) {
    __shared__ char smem[2][CB32];
    __shared__ float tbs[NO * 4];
    __shared__ u64 kk[16][32];
    __shared__ u64 pb2[16][4];

    const int b = blockIdx.y;
    const int span = blockIdx.x;
    const int lane = threadIdx.x;
    const size_t bbase = (size_t)b * NP;
    const char* gpred = (const char*)pred;

    char* cur = smem[0];
    char* nxt = smem[1];

    const int rho = lane >> 1;
    const int h = lane & 1;
    const int c0 = rho & 3;
    const int Ab = 16 * (21 * rho + (rho >> 2));
    const int sbase = h ? 11 : 1;

    tbs[lane] = tboxes[b * NO * 4 + lane];

    u64 ok[8];
#pragma unroll
    for (int j = 0; j < 8; ++j) ok[j] = 0ull;

    float my_ll = 0.f, my_ce = 0.f;
    int my_np = 0;

    int chunk = span;
    int next_chunk = chunk + SPB2;
    {
        float4 vreg[11];
        stage_load(vreg, gpred, b, chunk * 32, lane);
        stage_write(cur, vreg, lane);
    }

    while (chunk < CHB32) {
        float4 vreg[11];
        const bool have_next = (next_chunk < CHB32);
        if (have_next)
            stage_load(vreg, gpred, b, next_chunk * 32, lane);

        const int r0 = chunk * 32;
        const int nrows = min(32, NP - r0);
        const int p = r0 + rho;
        const bool rok = (rho < nrows);

        float4 v[11];
#pragma unroll
        for (int k = 0; k < 11; ++k)
            v[k] = *(const float4*)(cur + Ab + 16 * (sbase + k));

        float vals[44];
#pragma unroll
        for (int k = 0; k < 11; ++k) {
            const float xs[4] = {v[k].x, v[k].y, v[k].z, v[k].w};
#pragma unroll
            for (int t = 0; t < 4; ++t) {
                bool okv;
                if (k == 0)
                    okv = h ? false : (t >= c0);
                else if (k == 10)
                    okv = h ? (t <= c0) : true;
                else
                    okv = true;
                vals[4 * k + t] = okv ? xs[t] : NEG_HUGE;
            }
        }
        float mA = vals[0], mB = vals[1];
#pragma unroll
        for (int j = 2; j < 44; j += 2) {
            mA = fmaxf(mA, vals[j]);
            mB = fmaxf(mB, vals[j + 1]);
        }
        float m = fmaxf(mA, mB);
        m = fmaxf(m, __shfl_xor(m, 1, 64));

        float sA = 0.f, sB = 0.f;
#pragma unroll
        for (int j = 0; j < 44; j += 2) {
            sA += __expf(vals[j] - m);
            sB += __expf(vals[j + 1] - m);
        }
        float ssum = sA + sB;
        ssum += __shfl_xor(ssum, 1, 64);
        const float lse = m + __logf(ssum);

        // fused IoU loop: row decision + per-o argmax byproduct
        float bv = -1.f;
        int bi = 0;
        {
            const float4 pq = rok ? *((const float4*)priors + p)
                                  : make_float4(0.f, 0.f, 1.f, 1.f);
            const float prl = pq.x - pq.z * 0.5f, prt = pq.y - pq.w * 0.5f;
            const float prr2 = pq.x + pq.z * 0.5f, prb = pq.y + pq.w * 0.5f;
            const float parea = (prr2 - prl) * (prb - prt);
            const int obase = h * 8;
#pragma unroll
            for (int oj = 0; oj < 8; ++oj) {
                const int o = obase + oj;
                const float al = tbs[o * 4 + 0], at = tbs[o * 4 + 1];
                const float ar = tbs[o * 4 + 2], ab = tbs[o * 4 + 3];
                float iw = fminf(ar, prr2) - fmaxf(al, prl); iw = fmaxf(iw, 0.f);
                float ih = fminf(ab, prb) - fmaxf(at, prt); ih = fmaxf(ih, 0.f);
                const float inter = iw * ih;
                const float aarea = (ar - al) * (ab - at);
                const float iou = inter / (aarea + parea - inter);
                if (iou > bv) { bv = iou; bi = o; }
                if (rok) {
                    const u64 key = ((u64)__float_as_uint(iou) << 32) |
                                    (u64)(0xFFFFFFFFu - (unsigned)p);
                    ok[oj] = (key > ok[oj]) ? key : ok[oj];
                }
            }
            const float ov = __shfl_xor(bv, 1, 64);
            const int oi = __shfl_xor(bi, 1, 64);
            if (ov > bv || (ov == bv && oi < bi)) { bv = ov; bi = oi; }
        }

        if (h == 0 && rok) {
            const float bg = (c0 == 0) ? v[0].x : (c0 == 1) ? v[0].y
                           : (c0 == 2) ? v[0].z : v[0].w;
            const bool pos = (bv >= THRESH_F);     // UNFORCED
            const int o = bi;
            lr[bbase + p] = pos ? 0.f : (lse - bg);
            if (pos) {
                my_np += 1;
                const float* rowp = (const float*)(cur + 340 * rho);
                const int lbl = tlabels[b * NO + o] + 1;
                my_ce += lse - rowp[4 + lbl];
                const float4 pq = *((const float4*)priors + p);
                my_ll += sl1enc(rowp[0], rowp[1], rowp[2], rowp[3], pq,
                                &tbs[o * 4]);
            }
        }

        if (have_next)
            stage_write(nxt, vreg, lane);

        chunk = next_chunk;
        next_chunk += SPB2;
        char* tmp = cur; cur = nxt; nxt = tmp;
    }

    // per-block partial reduce (plain stores -> no init/atomics needed)
    for (int d2 = 1; d2 < 64; d2 <<= 1) {
        my_ll += __shfl_xor(my_ll, d2, 64);
        my_ce += __shfl_xor(my_ce, d2, 64);
        my_np += __shfl_xor(my_np, d2, 64);
    }
    if (lane == 0) {
        pll[b * SPB2 + span] = my_ll;
        pce[b * SPB2 + span] = my_ce;
        pnp[b * SPB2 + span] = (float)my_np;
    }

    // per-o block candidate reduce: kk[16][32] -> pb2[16][4] -> bcand
#pragma unroll
    for (int j = 0; j < 8; ++j) kk[h * 8 + j][rho] = ok[j];
    __syncthreads();
    {
        const int o = lane >> 2, seg = lane & 3;
        u64 m2 = 0ull;
#pragma unroll
        for (int i = 0; i < 8; ++i) {
            const u64 vv = kk[o][seg * 8 + i];
            m2 = (vv > m2) ? vv : m2;
        }
        pb2[o][seg] = m2;
    }
    __syncthreads();
    if (lane < NO) {
        u64 m2 = pb2[lane][0];
#pragma unroll
        for (int i = 1; i < 4; ++i) {
            const u64 vv = pb2[lane][i];
            m2 = (vv > m2) ? vv : m2;
        }
        bcand[((size_t)b * NO + lane) * SPB2 + span] = m2;
    }
}

// ---------------------------------------------------------------- select
// R22: prologue reduces bcand -> forced rows (<=16/b), applies Delta-
// corrections (quad lse recompute) and zeroes lrk at forced-unforced-neg
// rows BEFORE the register-cache load; then the 3-pass radix as before.
__global__ __launch_bounds__(1024) void k_select(
    const float* __restrict__ pred, const float* __restrict__ tboxes,
    const int* __restrict__ tlabels, const float* __restrict__ priors,
    float* __restrict__ lrk, const u64* __restrict__ bcand,
    const float* __restrict__ pll, const float* __restrict__ pce,
    const float* __restrict__ pnp, float* __restrict__ pout) {
    const int b = blockIdx.x;
    const int tid = threadIdx.x;
    const int lane = tid & 63;
    const int wid = tid >> 6;
    const int sub = lane & 15;

    __shared__ unsigned hist16[2048][16];  // 128 KiB
    __shared__ unsigned chist[2048];
    __shared__ int sh_bucket, sh_knew;
    __shared__ float wsum[16];
    __shared__ int wcnt[16];
    __shared__ float tbs[NO * 4];
    __shared__ int tl[NO];
    __shared__ u64 pbq[16][4];
    __shared__ int p16s[16];
    __shared__ float sparts[56 * 3];
    __shared__ float sll, sce, snp_f;
    __shared__ float fll, fce;
    __shared__ int fnp;

    // phase A: loads + candidate partial reduce + partial-sum staging
    if (tid < NO * 4) tbs[tid] = tboxes[b * NO * 4 + tid];
    if (tid >= 128 && tid < 128 + NO) tl[tid - 128] = tlabels[b * NO + tid - 128];
    if (tid < 64) {
        const int o = tid & 15, grp = tid >> 4;
        const u64* c = bcand + ((size_t)b * NO + o) * SPB2 + grp * 14;
        u64 m = 0ull;
        for (int i = 0; i < 14; ++i) {
            const u64 v = c[i];
            m = (v > m) ? v : m;
        }
        pbq[o][grp] = m;
    }
    if (tid >= 64 && tid < 120) {
        const int l = tid - 64;
        sparts[l * 3 + 0] = pll[b * SPB2 + l];
        sparts[l * 3 + 1] = pce[b * SPB2 + l];
        sparts[l * 3 + 2] = pnp[b * SPB2 + l];
    }
    __syncthreads();
    // phase B: finalize p16s + serial partial sums
    if (tid < NO) {
        u64 m = pbq[tid][0];
#pragma unroll
        for (int i = 1; i < 4; ++i) {
            const u64 v = pbq[tid][i];
            m = (v > m) ? v : m;
        }
        p16s[tid] = (int)(0xFFFFFFFFu - (unsigned)(m & 0xFFFFFFFFull));
    }
    if (tid == 32) {
        float a = 0.f, c = 0.f, n = 0.f;
        for (int l = 0; l < 56; ++l) {
            a += sparts[l * 3 + 0];
            c += sparts[l * 3 + 1];
            n += sparts[l * 3 + 2];
        }
        sll = a; sce = c; snp_f = n;
    }
    __syncthreads();
    // phase C: fixup (wave 0; 4 lanes per forced slot)
    if (tid < 64) {
        const int g = lane >> 2, q = lane & 3;
        const int p = p16s[g];
        bool winner = true;
        for (int o2 = g + 1; o2 < NO; ++o2)
            if (p16s[o2] == p) winner = false;
        float dll = 0.f, dce = 0.f;
        int dnp = 0;
        if (winner) {
            const float* base = pred + (size_t)b * NP * ND;
            const int A = 21 * p + (p >> 2), c0 = p & 3;
            const float4* vp = (const float4*)base + A;
            // quad masked lse (R6-verified masking)
            float vals[24];
#pragma unroll
            for (int k = 0; k < 6; ++k) {
                const int s = q + 4 * k;
                const float4 f4 = vp[(s <= 21) ? s : 21];
                const float xs[4] = {f4.x, f4.y, f4.z, f4.w};
#pragma unroll
                for (int t = 0; t < 4; ++t) {
                    const int d = 4 * s + t - c0;
                    vals[4 * k + t] =
                        (s <= 21 && d >= 4 && d <= 84) ? xs[t] : NEG_HUGE;
                }
            }
            float mx = vals[0];
#pragma unroll
            for (int j = 1; j < 24; ++j) mx = fmaxf(mx, vals[j]);
            mx = fmaxf(mx, __shfl_xor(mx, 1, 64));
            mx = fmaxf(mx, __shfl_xor(mx, 2, 64));
            float es = 0.f;
#pragma unroll
            for (int j = 0; j < 24; ++j) es += __expf(vals[j] - mx);
            es += __shfl_xor(es, 1, 64);
            es += __shfl_xor(es, 2, 64);
            const float lse = mx + __logf(es);
            // unforced best-truth for row p (4 o's per lane)
            const float4 pq = *((const float4*)priors + p);
            const float prl = pq.x - pq.z * 0.5f, prt = pq.y - pq.w * 0.5f;
            const float prr2 = pq.x + pq.z * 0.5f, prb = pq.y + pq.w * 0.5f;
            const float parea = (prr2 - prl) * (prb - prt);
            float bv = -1.f;
            int bi = 0;
#pragma unroll
            for (int jj = 0; jj < 4; ++jj) {
                const int o2 = q * 4 + jj;
                const float al = tbs[o2 * 4 + 0], at = tbs[o2 * 4 + 1];
                const float ar = tbs[o2 * 4 + 2], ab = tbs[o2 * 4 + 3];
                float iw = fminf(ar, prr2) - fmaxf(al, prl); iw = fmaxf(iw, 0.f);
                float ih = fminf(ab, prb) - fmaxf(at, prt); ih = fmaxf(ih, 0.f);
                const float inter = iw * ih;
                const float aarea = (ar - al) * (ab - at);
                const float iou = inter / (aarea + parea - inter);
                if (iou > bv) { bv = iou; bi = o2; }
            }
#pragma unroll
            for (int d = 1; d <= 2; d <<= 1) {
                const float ov = __shfl_xor(bv, d, 64);
                const int oi = __shfl_xor(bi, d, 64);
                if (ov > bv || (ov == bv && oi < bi)) { bv = ov; bi = oi; }
            }
            if (q == 0) {
                const float* rowp = base + (size_t)p * ND;
                const float l0 = rowp[0], l1 = rowp[1];
                const float l2 = rowp[2], l3 = rowp[3];
                const bool was_pos = (bv >= THRESH_F);
                const float ce_f = lse - rowp[4 + tl[g] + 1];
                const float ll_f = sl1enc(l0, l1, l2, l3, pq, &tbs[g * 4]);
                if (was_pos) {
                    const float ce_nf = lse - rowp[4 + tl[bi] + 1];
                    const float ll_nf = sl1enc(l0, l1, l2, l3, pq, &tbs[bi * 4]);
                    dll = ll_f - ll_nf;
                    dce = ce_f - ce_nf;
                } else {
                    dll = ll_f;
                    dce = ce_f;
                    dnp = 1;
                    lrk[(size_t)b * NP + p] = 0.f;   // forced row leaves neg set
                }
            }
        }
        for (int d2 = 1; d2 < 64; d2 <<= 1) {
            dll += __shfl_xor(dll, d2, 64);
            dce += __shfl_xor(dce, d2, 64);
            dnp += __shfl_xor(dnp, d2, 64);
        }
        if (lane == 0) { fll = dll; fce = dce; fnp = dnp; }
    }
    __threadfence_block();
    __syncthreads();

    const float llb = sll + fll;
    const float ceb = sce + fce;
    const int npb = (int)(snp_f + 0.5f) + fnp;

    // phase D: register-cache + 3-pass radix (post-fix lrk)
    const float4* row4 = (const float4*)(lrk + (size_t)b * NP);
    float4 cch[7];
    bool cvz[7];
#pragma unroll
    for (int j = 0; j < 7; ++j) {
        const int i = tid + j * 1024;
        cvz[j] = (i < NP / 4);
        cch[j] = cvz[j] ? row4[i] : make_float4(0.f, 0.f, 0.f, 0.f);
    }

    const int K0 = min(npb * NEGPOS_I, NP);
    int k = K0;
    unsigned prefix = 0;
    const int shifts[3] = {21, 10, 0};
    const unsigned masks[3] = {0u, 0xFFE00000u, 0xFFFFFC00u};

    for (int pass = 0; pass < 3; ++pass) {
        const int shift = shifts[pass];
        const unsigned mask_hi = masks[pass];
        {
            uint4* hz = (uint4*)hist16;
            for (int j = tid; j < 2048 * 4; j += 1024)
                hz[j] = make_uint4(0u, 0u, 0u, 0u);
        }
        __syncthreads();
#pragma unroll
        for (int j = 0; j < 7; ++j) {
            if (cvz[j]) {
                const float4 v4 = cch[j];
#pragma unroll
                for (int c = 0; c < 4; ++c) {
                    const float f = (c == 0) ? v4.x : (c == 1) ? v4.y
                                  : (c == 2) ? v4.z : v4.w;
                    const unsigned v = __float_as_uint(f);
                    if ((v & mask_hi) == (prefix & mask_hi))
                        atomicAdd(&hist16[(v >> shift) & 2047u][sub], 1u);
                }
            }
        }
        __syncthreads();
        for (int j = tid; j < 2048; j += 1024) {
            const uint4* hp = (const uint4*)&hist16[j][0];
            const uint4 a = hp[0], b4 = hp[1], c4 = hp[2], d4 = hp[3];
            chist[j] = a.x + a.y + a.z + a.w + b4.x + b4.y + b4.z + b4.w +
                       c4.x + c4.y + c4.z + c4.w + d4.x + d4.y + d4.z + d4.w;
        }
        __syncthreads();
        if (tid < 64) {
            unsigned g = 0;
            for (int j = 0; j < 32; ++j) g += chist[lane * 32 + j];
            unsigned T = g;
            for (int d = 1; d < 64; d <<= 1) {
                const unsigned t = __shfl_down(T, d, 64);
                if (lane + d < 64) T += t;
            }
            const unsigned E = T - g;
            const bool hit = (E < (unsigned)k) && ((unsigned)k <= T);
            const unsigned long long msk = __ballot(hit);
            const int wl = __ffsll(msk) - 1;
            if (lane == wl) {
                unsigned cum = E;
                int bsel = lane * 32, kn = k;
                for (int j = 31; j >= 0; --j) {
                    const unsigned c = chist[lane * 32 + j];
                    if (cum + c >= (unsigned)k) {
                        bsel = lane * 32 + j;
                        kn = k - (int)cum;
                        break;
                    }
                    cum += c;
                }
                sh_bucket = bsel;
                sh_knew = kn;
            }
        }
        __syncthreads();
        prefix |= ((unsigned)sh_bucket) << shift;
        k = sh_knew;
        __syncthreads();
    }
    const float T = __uint_as_float(prefix);

    float msum = 0.f;
    int mcnt = 0;
#pragma unroll
    for (int j = 0; j < 7; ++j) {
        if (cvz[j]) {
            const float4 v4 = cch[j];
#pragma unroll
            for (int c = 0; c < 4; ++c) {
                const float f = (c == 0) ? v4.x : (c == 1) ? v4.y
                              : (c == 2) ? v4.z : v4.w;
                if (__float_as_uint(f) > prefix) { msum += f; mcnt++; }
            }
        }
    }
    for (int s = 32; s > 0; s >>= 1) {
        msum += __shfl_down(msum, s, 64);
        mcnt += __shfl_down(mcnt, s, 64);
    }
    if (lane == 0) { wsum[wid] = msum; wcnt[wid] = mcnt; }
    __syncthreads();
    if (tid == 0) {
        float tot = 0.f;
        int cnt = 0;
        for (int w = 0; w < 16; ++w) { tot += wsum[w]; cnt += wcnt[w]; }
        const float negsum = tot + (float)(K0 - cnt) * T;
        pout[b * 4 + 0] = llb;
        pout[b * 4 + 1] = ceb + negsum;
        pout[b * 4 + 2] = (float)npb;
    }
}

// ---------------------------------------------------------------- final
__global__ void k_final(const float* __restrict__ pout,
                        float* __restrict__ out) {
    if (threadIdx.x == 0 && blockIdx.x == 0) {
        float a0 = 0.f, a1 = 0.f, n = 0.f;
        for (int b = 0; b < NB; ++b) {
            a0 += pout[b * 4 + 0];
            a1 += pout[b * 4 + 1];
            n += pout[b * 4 + 2];
        }
        out[0] = a0 / n;
        out[1] = a1 / n;
    }
}

extern "C" void kernel_launch(void* const* d_in, const int* in_sizes, int n_in,
                              void* d_out, int out_size, void* d_ws, size_t ws_size,
                              hipStream_t stream) {
    const float* pred   = (const float*)d_in[0];
    const float* tboxes = (const float*)d_in[1];
    const int*   tlabels = (const int*)d_in[2];
    const float* priors = (const float*)d_in[3];
    float* out = (float*)d_out;

    char* w = (char*)d_ws;
    float* lrk  = (float*)w;                                  // 4*BPCNT
    u64*   bcand = (u64*)(w + 4ull * BPCNT);                  // NB*NO*SPB2 u64
    char*  w2 = w + 4ull * BPCNT + 8ull * NB * NO * SPB2;
    float* pll = (float*)w2;                                  // NB*SPB2
    float* pce = (float*)(w2 + 4ull * NB * SPB2);
    float* pnp = (float*)(w2 + 8ull * NB * SPB2);
    float* pout = (float*)(w2 + 12ull * NB * SPB2);           // NB*4

    k_main<<<dim3(SPB2, NB), dim3(64), 0, stream>>>(
        pred, tboxes, tlabels, priors, lrk, bcand, pll, pce, pnp);
    k_select<<<dim3(NB), dim3(1024), 0, stream>>>(
        pred, tboxes, tlabels, priors, lrk, bcand, pll, pce, pnp, pout);
    k_final<<<dim3(1), dim3(1), 0, stream>>>(pout, out);
}